// Round 3
// baseline (250.197 us; speedup 1.0000x reference)
//
#include <hip/hip_runtime.h>
#include <math.h>

#define NLV 16
#define TBL (1u << 19)
#define HMASK (TBL - 1u)
#define PRIME1 2654435761u

struct Scales { float s[NLV]; };

// Forced-MLP structure: issue ALL 64 table gathers for a point, then a
// hard scheduler fence (sched_barrier(0)) so the compiler cannot sink
// loads to their uses (round-2 failure: VGPR stayed 36 = loads serialized).
// f[16][4] float2 results stay live across the fence -> ~64 loads in
// flight per wave. launch_bounds(256,2): VGPR cap 256, no spill.
__global__ __launch_bounds__(256, 2) void hashgrid_mlp_kernel(
    const float2* __restrict__ pts,
    const float2* __restrict__ table,   // [16][524288] float2
    const float*  __restrict__ W1,      // [64][32]
    const float*  __restrict__ W2,      // [3][64]
    float* __restrict__ out,            // [N][3]
    int N, Scales sc)
{
    int i = blockIdx.x * 256 + threadIdx.x;
    if (i >= N) return;

    float2 p = pts[i];

    float2 f[NLV][4];
    float fx[NLV], fy[NLV];

#pragma unroll
    for (int l = 0; l < NLV; ++l) {
        float s  = sc.s[l];
        float px = p.x * s;              // f32 mul, bitwise == reference
        float py = p.y * s;
        float fpx = floorf(px), fpy = floorf(py);
        fx[l] = px - fpx;
        fy[l] = py - fpy;
        unsigned bx = (unsigned)(int)fpx;
        unsigned by = (unsigned)(int)fpy;
        unsigned hy0 = by * PRIME1;
        unsigned hy1 = hy0 + PRIME1;     // (by+1)*PRIME1 mod 2^32
        const float2* tl = table + (size_t)l * TBL;
        f[l][0] = tl[( bx        ^ hy0) & HMASK];
        f[l][1] = tl[( bx        ^ hy1) & HMASK];
        f[l][2] = tl[((bx + 1u)  ^ hy0) & HMASK];
        f[l][3] = tl[((bx + 1u)  ^ hy1) & HMASK];
    }

    // Hard fence: all 64 gathers issued above must stay above; the interp
    // below cannot be hoisted up, and the loads cannot be sunk down.
    __builtin_amdgcn_sched_barrier(0);

    float enc[32];
#pragma unroll
    for (int l = 0; l < NLV; ++l) {
        float gx = 1.f - fx[l], gy = 1.f - fy[l];
        float w00 = gx * gy,   w01 = gx * fy[l];
        float w10 = fx[l] * gy, w11 = fx[l] * fy[l];
        enc[2*l]   = w00*f[l][0].x + w01*f[l][1].x + w10*f[l][2].x + w11*f[l][3].x;
        enc[2*l+1] = w00*f[l][0].y + w01*f[l][1].y + w10*f[l][2].y + w11*f[l][3].y;
    }

    float o0 = 0.f, o1 = 0.f, o2 = 0.f;
#pragma unroll
    for (int j = 0; j < 64; ++j) {
        float h = 0.f;
#pragma unroll
        for (int k = 0; k < 32; ++k)
            h = fmaf(enc[k], W1[j*32 + k], h);   // W1 addr uniform -> s_load
        h = fmaxf(h, 0.f);
        o0 = fmaf(h, W2[      j], o0);
        o1 = fmaf(h, W2[ 64 + j], o1);
        o2 = fmaf(h, W2[128 + j], o2);
    }
    out[3*i + 0] = o0;
    out[3*i + 1] = o1;
    out[3*i + 2] = o2;
}

extern "C" void kernel_launch(void* const* d_in, const int* in_sizes, int n_in,
                              void* d_out, int out_size, void* d_ws, size_t ws_size,
                              hipStream_t stream) {
    const float2* pts   = (const float2*)d_in[0];
    const float2* table = (const float2*)d_in[1];
    const float*  W1    = (const float*)d_in[2];
    const float*  W2    = (const float*)d_in[3];
    float* out = (float*)d_out;
    int N = in_sizes[0] / 2;

    // Replicate numpy: np.floor(16 * 1.447269237440378 ** arange(16)).astype(f32)
    // Host pow == glibc pow == numpy's npy_pow -> bit-identical scales
    // (level 15 is a floor boundary: comes out 4095, NOT 4096).
    Scales sc;
    for (int l = 0; l < NLV; ++l)
        sc.s[l] = (float)floor(16.0 * pow(1.447269237440378, (double)l));

    int blocks = (N + 255) / 256;
    hipLaunchKernelGGL(hashgrid_mlp_kernel, dim3(blocks), dim3(256), 0, stream,
                       pts, table, W1, W2, out, N, sc);
}